// Round 1
// baseline (11508.208 us; speedup 1.0000x reference)
//
#include <hip/hip_runtime.h>
#include <math.h>

#define IN_C 128
#define HID 32
#define HEADS 4
#define OUT_C 128
#define NEG_SLOPE 0.2f

// ---------- atomic float max via mixed int/uint trick ----------
// init pattern 0xFFFFFFFF (neg-NaN) behaves as "smaller than everything":
//  - int atomicMax: 0xFFFFFFFF == -1, any float>=0 pattern > -1  -> replaces
//  - uint atomicMin: 0xFFFFFFFF is max uint, any pattern < it    -> replaces
__device__ __forceinline__ void atomicMaxF(float* addr, float val) {
    if (val == 0.0f) val = 0.0f;  // canonicalize -0.0 -> +0.0
    if (val >= 0.0f) {
        atomicMax((int*)addr, __float_as_int(val));
    } else {
        atomicMin((unsigned int*)addr, __float_as_uint(val));
    }
}

// ---------- dual transform: out_l = x@Wl, out_r = x@Wr  (K=M=128) ----------
#define TROWS 8
__global__ void transform_dual(const float* __restrict__ x,
                               const float* __restrict__ Wl,
                               const float* __restrict__ Wr,
                               float* __restrict__ outl,
                               float* __restrict__ outr, int n) {
    __shared__ float xs[TROWS][IN_C];
    const int t = threadIdx.x;          // 0..127, output column
    const int row0 = blockIdx.x * TROWS;
#pragma unroll
    for (int r = 0; r < TROWS; ++r) {
        int row = row0 + r;
        xs[r][t] = (row < n) ? x[(size_t)row * IN_C + t] : 0.0f;
    }
    __syncthreads();
    float accl[TROWS] = {0.f, 0.f, 0.f, 0.f, 0.f, 0.f, 0.f, 0.f};
    float accr[TROWS] = {0.f, 0.f, 0.f, 0.f, 0.f, 0.f, 0.f, 0.f};
    for (int k = 0; k < IN_C; ++k) {
        float wl = Wl[k * IN_C + t];
        float wr = Wr[k * IN_C + t];
#pragma unroll
        for (int r = 0; r < TROWS; ++r) {
            float xv = xs[r][k];        // broadcast, conflict-free
            accl[r] = fmaf(xv, wl, accl[r]);
            accr[r] = fmaf(xv, wr, accr[r]);
        }
    }
#pragma unroll
    for (int r = 0; r < TROWS; ++r) {
        int row = row0 + r;
        if (row < n) {
            outl[(size_t)row * IN_C + t] = accl[r];
            outr[(size_t)row * IN_C + t] = accr[r];
        }
    }
}

// ---------- layer 1 edge scores: e[eh] = sum_c lrelu(xl[s]+xr[d])*att ----------
__global__ void edge_score1(const float* __restrict__ xl,
                            const float* __restrict__ xr,
                            const float* __restrict__ att,
                            const int* __restrict__ src,
                            const int* __restrict__ dst,
                            float* __restrict__ ebuf,
                            float* __restrict__ mx, int E) {
    int idx = blockIdx.x * blockDim.x + threadIdx.x;
    if (idx >= E * HEADS) return;
    int e = idx >> 2, h = idx & 3;
    int s = src[e], d = dst[e];
    const float4* pl = (const float4*)(xl + (size_t)s * IN_C + h * HID);
    const float4* pr = (const float4*)(xr + (size_t)d * IN_C + h * HID);
    const float4* pa = (const float4*)(att + h * HID);
    float acc = 0.0f;
#pragma unroll
    for (int i = 0; i < HID / 4; ++i) {
        float4 a = pl[i], b = pr[i], c = pa[i];
        float m;
        m = a.x + b.x; acc += (m > 0.f ? m : NEG_SLOPE * m) * c.x;
        m = a.y + b.y; acc += (m > 0.f ? m : NEG_SLOPE * m) * c.y;
        m = a.z + b.z; acc += (m > 0.f ? m : NEG_SLOPE * m) * c.z;
        m = a.w + b.w; acc += (m > 0.f ? m : NEG_SLOPE * m) * c.w;
    }
    ebuf[idx] = acc;
    atomicMaxF(&mx[d * HEADS + h], acc);
}

__global__ void edge_exp1(float* __restrict__ ebuf,
                          const float* __restrict__ mx,
                          float* __restrict__ denom,
                          const int* __restrict__ dst, int E) {
    int idx = blockIdx.x * blockDim.x + threadIdx.x;
    if (idx >= E * HEADS) return;
    int e = idx >> 2, h = idx & 3;
    int d = dst[e];
    float v = expf(ebuf[idx] - mx[d * HEADS + h]);
    ebuf[idx] = v;
    atomicAdd(&denom[d * HEADS + h], v);
}

__global__ void aggregate1(const float* __restrict__ ebuf,
                           const float* __restrict__ denom,
                           const float* __restrict__ xl,
                           const int* __restrict__ src,
                           const int* __restrict__ dst,
                           float* __restrict__ out, int E) {
    int idx = blockIdx.x * blockDim.x + threadIdx.x;
    if (idx >= E * HEADS) return;
    int e = idx >> 2, h = idx & 3;
    int s = src[e], d = dst[e];
    float alpha = ebuf[idx] / denom[d * HEADS + h];
    const float4* pl = (const float4*)(xl + (size_t)s * IN_C + h * HID);
    float* po = out + (size_t)d * IN_C + h * HID;
#pragma unroll
    for (int i = 0; i < HID / 4; ++i) {
        float4 a = pl[i];
        atomicAdd(po + 4 * i + 0, alpha * a.x);
        atomicAdd(po + 4 * i + 1, alpha * a.y);
        atomicAdd(po + 4 * i + 2, alpha * a.z);
        atomicAdd(po + 4 * i + 3, alpha * a.w);
    }
}

// h = elu(acc + b1) in place
__global__ void finalize1(float* __restrict__ h, const float* __restrict__ b,
                          int total) {
    int i = blockIdx.x * blockDim.x + threadIdx.x;
    if (i >= total) return;
    float v = h[i] + b[i & (IN_C - 1)];
    h[i] = (v > 0.f) ? v : expm1f(v);
}

// ---------- layer 2 (single head, C=128) ----------
__global__ void edge_score2(const float* __restrict__ hl,
                            const float* __restrict__ hr,
                            const float* __restrict__ att,
                            const int* __restrict__ src,
                            const int* __restrict__ dst,
                            float* __restrict__ ebuf,
                            float* __restrict__ mx, int E) {
    int e = blockIdx.x * blockDim.x + threadIdx.x;
    if (e >= E) return;
    int s = src[e], d = dst[e];
    const float4* pl = (const float4*)(hl + (size_t)s * OUT_C);
    const float4* pr = (const float4*)(hr + (size_t)d * OUT_C);
    const float4* pa = (const float4*)att;
    float acc = 0.0f;
#pragma unroll
    for (int i = 0; i < OUT_C / 4; ++i) {
        float4 a = pl[i], b = pr[i], c = pa[i];
        float m;
        m = a.x + b.x; acc += (m > 0.f ? m : NEG_SLOPE * m) * c.x;
        m = a.y + b.y; acc += (m > 0.f ? m : NEG_SLOPE * m) * c.y;
        m = a.z + b.z; acc += (m > 0.f ? m : NEG_SLOPE * m) * c.z;
        m = a.w + b.w; acc += (m > 0.f ? m : NEG_SLOPE * m) * c.w;
    }
    ebuf[e] = acc;
    atomicMaxF(&mx[d], acc);
}

__global__ void edge_exp2(float* __restrict__ ebuf,
                          const float* __restrict__ mx,
                          float* __restrict__ denom,
                          const int* __restrict__ dst, int E) {
    int e = blockIdx.x * blockDim.x + threadIdx.x;
    if (e >= E) return;
    int d = dst[e];
    float v = expf(ebuf[e] - mx[d]);
    ebuf[e] = v;
    atomicAdd(&denom[d], v);
}

__global__ void aggregate2(const float* __restrict__ ebuf,
                           const float* __restrict__ denom,
                           const float* __restrict__ hl,
                           const int* __restrict__ src,
                           const int* __restrict__ dst,
                           float* __restrict__ out, int E) {
    int idx = blockIdx.x * blockDim.x + threadIdx.x;
    if (idx >= E * 4) return;
    int e = idx >> 2, q = idx & 3;           // quarter of the 128-wide row
    int s = src[e], d = dst[e];
    float alpha = ebuf[e] / denom[d];
    const float4* pl = (const float4*)(hl + (size_t)s * OUT_C + q * 32);
    float* po = out + (size_t)d * OUT_C + q * 32;
#pragma unroll
    for (int i = 0; i < 8; ++i) {
        float4 a = pl[i];
        atomicAdd(po + 4 * i + 0, alpha * a.x);
        atomicAdd(po + 4 * i + 1, alpha * a.y);
        atomicAdd(po + 4 * i + 2, alpha * a.z);
        atomicAdd(po + 4 * i + 3, alpha * a.w);
    }
}

__global__ void finalize2(const float* __restrict__ acc,
                          const float* __restrict__ b,
                          float* __restrict__ out, int total) {
    int i = blockIdx.x * blockDim.x + threadIdx.x;
    if (i >= total) return;
    out[i] = acc[i] + b[i & (OUT_C - 1)];
}

extern "C" void kernel_launch(void* const* d_in, const int* in_sizes, int n_in,
                              void* d_out, int out_size, void* d_ws, size_t ws_size,
                              hipStream_t stream) {
    const float* x    = (const float*)d_in[0];
    const int*   ei   = (const int*)d_in[1];
    const float* W1l  = (const float*)d_in[2];
    const float* W1r  = (const float*)d_in[3];
    const float* att1 = (const float*)d_in[4];
    const float* b1   = (const float*)d_in[5];
    const float* W2l  = (const float*)d_in[6];
    const float* W2r  = (const float*)d_in[7];
    const float* att2 = (const float*)d_in[8];
    const float* b2   = (const float*)d_in[9];

    const int N = in_sizes[0] / IN_C;
    const int E = in_sizes[1] / 2;
    const int* src = ei;
    const int* dst = ei + E;

    // workspace layout (floats)
    float* ws = (float*)d_ws;
    size_t o = 0;
    float* xl   = ws + o; o += (size_t)N * IN_C;   // layer1 x@Wl  / layer2 h@W2l
    float* xr   = ws + o; o += (size_t)N * IN_C;   // layer1 x@Wr  / layer2 h@W2r
    float* hbuf = ws + o; o += (size_t)N * IN_C;   // layer1 accum -> h (post ELU)
    float* acc2 = ws + o; o += (size_t)N * OUT_C;  // layer2 accum
    float* ebuf = ws + o; o += (size_t)E * HEADS;  // edge scores / exp values
    float* mx1  = ws + o; o += (size_t)N * HEADS;
    float* den1 = ws + o; o += (size_t)N * HEADS;
    float* mx2  = ws + o; o += (size_t)N;
    float* den2 = ws + o; o += (size_t)N;

    hipMemsetAsync(hbuf, 0,    (size_t)N * IN_C  * 4, stream);
    hipMemsetAsync(acc2, 0,    (size_t)N * OUT_C * 4, stream);
    hipMemsetAsync(den1, 0,    (size_t)N * HEADS * 4, stream);
    hipMemsetAsync(den2, 0,    (size_t)N * 4,         stream);
    hipMemsetAsync(mx1,  0xFF, (size_t)N * HEADS * 4, stream);  // acts as -inf
    hipMemsetAsync(mx2,  0xFF, (size_t)N * 4,         stream);

    const int B = 256;
    // ---- layer 1 ----
    transform_dual<<<(N + TROWS - 1) / TROWS, 128, 0, stream>>>(x, W1l, W1r, xl, xr, N);
    edge_score1<<<(E * HEADS + B - 1) / B, B, 0, stream>>>(xl, xr, att1, src, dst, ebuf, mx1, E);
    edge_exp1<<<(E * HEADS + B - 1) / B, B, 0, stream>>>(ebuf, mx1, den1, dst, E);
    aggregate1<<<(E * HEADS + B - 1) / B, B, 0, stream>>>(ebuf, den1, xl, src, dst, hbuf, E);
    finalize1<<<(N * IN_C + B - 1) / B, B, 0, stream>>>(hbuf, b1, N * IN_C);
    // ---- layer 2 ----
    transform_dual<<<(N + TROWS - 1) / TROWS, 128, 0, stream>>>(hbuf, W2l, W2r, xl, xr, N);
    edge_score2<<<(E + B - 1) / B, B, 0, stream>>>(xl, xr, att2, src, dst, ebuf, mx2, E);
    edge_exp2<<<(E + B - 1) / B, B, 0, stream>>>(ebuf, mx2, den2, dst, E);
    aggregate2<<<(E * 4 + B - 1) / B, B, 0, stream>>>(ebuf, den2, xl, src, dst, acc2, E);
    finalize2<<<(N * OUT_C + B - 1) / B, B, 0, stream>>>(acc2, b2, (float*)d_out, N * OUT_C);
}

// Round 2
// 1049.385 us; speedup vs baseline: 10.9666x; 10.9666x over previous
//
#include <hip/hip_runtime.h>
#include <math.h>

#define IN_C 128
#define HID 32
#define HEADS 4
#define OUT_C 128
#define NEG_SLOPE 0.2f

// ---------- dual transform: out_l = x@Wl, out_r = x@Wr  (K=M=128) ----------
#define TROWS 8
__global__ void transform_dual(const float* __restrict__ x,
                               const float* __restrict__ Wl,
                               const float* __restrict__ Wr,
                               float* __restrict__ outl,
                               float* __restrict__ outr, int n) {
    __shared__ float xs[TROWS][IN_C];
    const int t = threadIdx.x;          // 0..127, output column
    const int row0 = blockIdx.x * TROWS;
#pragma unroll
    for (int r = 0; r < TROWS; ++r) {
        int row = row0 + r;
        xs[r][t] = (row < n) ? x[(size_t)row * IN_C + t] : 0.0f;
    }
    __syncthreads();
    float accl[TROWS] = {0.f, 0.f, 0.f, 0.f, 0.f, 0.f, 0.f, 0.f};
    float accr[TROWS] = {0.f, 0.f, 0.f, 0.f, 0.f, 0.f, 0.f, 0.f};
    for (int k = 0; k < IN_C; ++k) {
        float wl = Wl[k * IN_C + t];
        float wr = Wr[k * IN_C + t];
#pragma unroll
        for (int r = 0; r < TROWS; ++r) {
            float xv = xs[r][k];        // broadcast, conflict-free
            accl[r] = fmaf(xv, wl, accl[r]);
            accr[r] = fmaf(xv, wr, accr[r]);
        }
    }
#pragma unroll
    for (int r = 0; r < TROWS; ++r) {
        int row = row0 + r;
        if (row < n) {
            outl[(size_t)row * IN_C + t] = accl[r];
            outr[(size_t)row * IN_C + t] = accr[r];
        }
    }
}

// ---------- CSR build: histogram -> exclusive scan -> position scatter ----------
__global__ void hist_kernel(const int* __restrict__ dst, int* __restrict__ cnt, int E) {
    int e = blockIdx.x * blockDim.x + threadIdx.x;
    if (e < E) atomicAdd(&cnt[dst[e]], 1);
}

// single-block exclusive scan over n counters (n ~ 50k), 1024 threads
__global__ void scan_excl(const int* __restrict__ cnt, int* __restrict__ rowptr, int n) {
    __shared__ int buf[1024];
    __shared__ int carry_s;
    const int t = threadIdx.x;
    if (t == 0) carry_s = 0;
    __syncthreads();
    for (int base = 0; base < n; base += 1024) {
        int i = base + t;
        int v = (i < n) ? cnt[i] : 0;
        int c = carry_s;
        buf[t] = v;
        __syncthreads();
        for (int off = 1; off < 1024; off <<= 1) {
            int add = (t >= off) ? buf[t - off] : 0;
            __syncthreads();
            buf[t] += add;
            __syncthreads();
        }
        int incl = buf[t];
        if (i < n) rowptr[i] = c + incl - v;   // exclusive
        __syncthreads();
        if (t == 1023) carry_s = c + incl;
        __syncthreads();
    }
    if (t == 0) rowptr[n] = carry_s;
}

__global__ void scatter_csr(const int* __restrict__ dst,
                            const int* __restrict__ rowptr,
                            int* __restrict__ cursor,
                            int* __restrict__ eids, int E) {
    int e = blockIdx.x * blockDim.x + threadIdx.x;
    if (e >= E) return;
    int d = dst[e];
    int pos = atomicAdd(&cursor[d], 1);
    eids[rowptr[d] + pos] = e;
}

// ---------- layer 1 edge scores: e[eh] = sum_c lrelu(xl[s]+xr[d])*att ----------
__global__ void edge_score1(const float* __restrict__ xl,
                            const float* __restrict__ xr,
                            const float* __restrict__ att,
                            const int* __restrict__ src,
                            const int* __restrict__ dst,
                            float* __restrict__ ebuf, int E) {
    int idx = blockIdx.x * blockDim.x + threadIdx.x;
    if (idx >= E * HEADS) return;
    int e = idx >> 2, h = idx & 3;
    int s = src[e], d = dst[e];
    const float4* pl = (const float4*)(xl + (size_t)s * IN_C + h * HID);
    const float4* pr = (const float4*)(xr + (size_t)d * IN_C + h * HID);
    const float4* pa = (const float4*)(att + h * HID);
    float acc = 0.0f;
#pragma unroll
    for (int i = 0; i < HID / 4; ++i) {
        float4 a = pl[i], b = pr[i], c = pa[i];
        float m;
        m = a.x + b.x; acc += (m > 0.f ? m : NEG_SLOPE * m) * c.x;
        m = a.y + b.y; acc += (m > 0.f ? m : NEG_SLOPE * m) * c.y;
        m = a.z + b.z; acc += (m > 0.f ? m : NEG_SLOPE * m) * c.z;
        m = a.w + b.w; acc += (m > 0.f ? m : NEG_SLOPE * m) * c.w;
    }
    ebuf[idx] = acc;
}

// ---------- per-node softmax + aggregation, layer 1 (4 heads x 32) ----------
// block = 128 threads: thread t -> output channel t, head h = t>>5, lane l = t&31
__global__ void node_agg1(const float* __restrict__ xl,
                          float* __restrict__ ebuf,          // [E*4] raw -> exp in place
                          const int* __restrict__ rowptr,
                          const int* __restrict__ eids,
                          const int* __restrict__ src,
                          const float* __restrict__ b,
                          float* __restrict__ hout, int N) {
    const int d = blockIdx.x;
    const int t = threadIdx.x;
    const int h = t >> 5, l = t & 31;
    const int beg = rowptr[d], end = rowptr[d + 1];
    __shared__ float mxs[HEADS], invden[HEADS];
    // phase 1: per-head max over incoming edges
    float m = -1e30f;
    for (int j = beg + l; j < end; j += 32) m = fmaxf(m, ebuf[eids[j] * 4 + h]);
#pragma unroll
    for (int o = 16; o >= 1; o >>= 1) m = fmaxf(m, __shfl_xor(m, o, 64));
    if (l == 0) mxs[h] = m;
    __syncthreads();
    // phase 2: exp in place + denom
    float mh = mxs[h];
    float s = 0.f;
    for (int j = beg + l; j < end; j += 32) {
        int e = eids[j];
        float v = __expf(ebuf[e * 4 + h] - mh);
        ebuf[e * 4 + h] = v;
        s += v;
    }
#pragma unroll
    for (int o = 16; o >= 1; o >>= 1) s += __shfl_xor(s, o, 64);
    if (l == 0) invden[h] = (s > 0.f) ? 1.f / s : 0.f;
    __syncthreads();
    // phase 3: weighted gather of source rows (coalesced 512B per edge)
    float inv = invden[h];
    float acc = 0.f;
    for (int j = beg; j < end; ++j) {
        int e = eids[j];
        float alpha = ebuf[e * 4 + h] * inv;
        acc = fmaf(alpha, xl[(size_t)src[e] * IN_C + t], acc);
    }
    float v = acc + b[t];
    hout[(size_t)d * IN_C + t] = (v > 0.f) ? v : expm1f(v);   // fused bias + ELU
}

// ---------- layer 2 edge scores (single head, C=128) ----------
__global__ void edge_score2(const float* __restrict__ hl,
                            const float* __restrict__ hr,
                            const float* __restrict__ att,
                            const int* __restrict__ src,
                            const int* __restrict__ dst,
                            float* __restrict__ ebuf, int E) {
    int e = blockIdx.x * blockDim.x + threadIdx.x;
    if (e >= E) return;
    int s = src[e], d = dst[e];
    const float4* pl = (const float4*)(hl + (size_t)s * OUT_C);
    const float4* pr = (const float4*)(hr + (size_t)d * OUT_C);
    const float4* pa = (const float4*)att;
    float acc = 0.0f;
#pragma unroll
    for (int i = 0; i < OUT_C / 4; ++i) {
        float4 a = pl[i], b = pr[i], c = pa[i];
        float m;
        m = a.x + b.x; acc += (m > 0.f ? m : NEG_SLOPE * m) * c.x;
        m = a.y + b.y; acc += (m > 0.f ? m : NEG_SLOPE * m) * c.y;
        m = a.z + b.z; acc += (m > 0.f ? m : NEG_SLOPE * m) * c.z;
        m = a.w + b.w; acc += (m > 0.f ? m : NEG_SLOPE * m) * c.w;
    }
    ebuf[e] = acc;
}

// ---------- per-node softmax + aggregation, layer 2 (1 head x 128) ----------
__global__ void node_agg2(const float* __restrict__ hl,
                          float* __restrict__ ebuf,          // [E] raw -> exp in place
                          const int* __restrict__ rowptr,
                          const int* __restrict__ eids,
                          const int* __restrict__ src,
                          const float* __restrict__ b,
                          float* __restrict__ out, int N) {
    const int d = blockIdx.x;
    const int t = threadIdx.x;       // 0..127
    const int beg = rowptr[d], end = rowptr[d + 1];
    __shared__ float red[2];
    __shared__ float mx_s, inv_s;
    // phase 1: max over all incoming edges
    float m = -1e30f;
    for (int j = beg + t; j < end; j += 128) m = fmaxf(m, ebuf[eids[j]]);
#pragma unroll
    for (int o = 32; o >= 1; o >>= 1) m = fmaxf(m, __shfl_xor(m, o, 64));
    if ((t & 63) == 0) red[t >> 6] = m;
    __syncthreads();
    if (t == 0) mx_s = fmaxf(red[0], red[1]);
    __syncthreads();
    float mh = mx_s;
    // phase 2: exp in place + denom
    float s = 0.f;
    for (int j = beg + t; j < end; j += 128) {
        int e = eids[j];
        float v = __expf(ebuf[e] - mh);
        ebuf[e] = v;
        s += v;
    }
#pragma unroll
    for (int o = 32; o >= 1; o >>= 1) s += __shfl_xor(s, o, 64);
    if ((t & 63) == 0) red[t >> 6] = s;
    __syncthreads();
    if (t == 0) {
        float tot = red[0] + red[1];
        inv_s = (tot > 0.f) ? 1.f / tot : 0.f;
    }
    __syncthreads();
    // phase 3: weighted gather
    float inv = inv_s;
    float acc = 0.f;
    for (int j = beg; j < end; ++j) {
        int e = eids[j];
        acc = fmaf(ebuf[e] * inv, hl[(size_t)src[e] * OUT_C + t], acc);
    }
    out[(size_t)d * OUT_C + t] = acc + b[t];
}

extern "C" void kernel_launch(void* const* d_in, const int* in_sizes, int n_in,
                              void* d_out, int out_size, void* d_ws, size_t ws_size,
                              hipStream_t stream) {
    const float* x    = (const float*)d_in[0];
    const int*   ei   = (const int*)d_in[1];
    const float* W1l  = (const float*)d_in[2];
    const float* W1r  = (const float*)d_in[3];
    const float* att1 = (const float*)d_in[4];
    const float* b1   = (const float*)d_in[5];
    const float* W2l  = (const float*)d_in[6];
    const float* W2r  = (const float*)d_in[7];
    const float* att2 = (const float*)d_in[8];
    const float* b2   = (const float*)d_in[9];

    const int N = in_sizes[0] / IN_C;
    const int E = in_sizes[1] / 2;
    const int* src = ei;
    const int* dst = ei + E;

    // workspace layout
    float* ws = (float*)d_ws;
    size_t o = 0;
    float* xl   = ws + o; o += (size_t)N * IN_C;   // x@Wl (layer1) / h@W2l (layer2)
    float* xr   = ws + o; o += (size_t)N * IN_C;   // x@Wr (layer1) / h@W2r (layer2)
    float* hbuf = ws + o; o += (size_t)N * IN_C;   // layer1 output h (post ELU)
    float* ebuf = ws + o; o += (size_t)E * HEADS;  // edge scores / exp values
    int* iws    = (int*)(ws + o);
    int* rowptr = iws;                 // N+1
    int* cnt    = iws + (N + 1);       // N   (cnt and cursor adjacent: one memset)
    int* cursor = iws + (N + 1) + N;   // N
    int* eids   = iws + (N + 1) + 2 * N;  // E

    hipMemsetAsync(cnt, 0, (size_t)2 * N * 4, stream);   // cnt + cursor

    const int B = 256;
    // ---- CSR by dst (shared by both layers) ----
    hist_kernel<<<(E + B - 1) / B, B, 0, stream>>>(dst, cnt, E);
    scan_excl<<<1, 1024, 0, stream>>>(cnt, rowptr, N);
    scatter_csr<<<(E + B - 1) / B, B, 0, stream>>>(dst, rowptr, cursor, eids, E);

    // ---- layer 1 ----
    transform_dual<<<(N + TROWS - 1) / TROWS, 128, 0, stream>>>(x, W1l, W1r, xl, xr, N);
    edge_score1<<<(E * HEADS + B - 1) / B, B, 0, stream>>>(xl, xr, att1, src, dst, ebuf, E);
    node_agg1<<<N, 128, 0, stream>>>(xl, ebuf, rowptr, eids, src, b1, hbuf, N);

    // ---- layer 2 ----
    transform_dual<<<(N + TROWS - 1) / TROWS, 128, 0, stream>>>(hbuf, W2l, W2r, xl, xr, N);
    edge_score2<<<(E + B - 1) / B, B, 0, stream>>>(xl, xr, att2, src, dst, ebuf, E);
    node_agg2<<<N, 128, 0, stream>>>(xl, ebuf, rowptr, eids, src, b2, (float*)d_out, N);
}

// Round 3
// 780.135 us; speedup vs baseline: 14.7516x; 1.3451x over previous
//
#include <hip/hip_runtime.h>
#include <math.h>

#define IN_C 128
#define HID 32
#define HEADS 4
#define OUT_C 128
#define NEG_SLOPE 0.2f
#define CAP 32          // edges cached per chunk (16 KB LDS rows)

// ---------- dual transform: out_l = x@Wl, out_r = x@Wr  (K=M=128) ----------
#define TROWS 8
__global__ void transform_dual(const float* __restrict__ x,
                               const float* __restrict__ Wl,
                               const float* __restrict__ Wr,
                               float* __restrict__ outl,
                               float* __restrict__ outr, int n) {
    __shared__ float xs[TROWS][IN_C];
    const int t = threadIdx.x;          // 0..127, output column
    const int row0 = blockIdx.x * TROWS;
#pragma unroll
    for (int r = 0; r < TROWS; ++r) {
        int row = row0 + r;
        xs[r][t] = (row < n) ? x[(size_t)row * IN_C + t] : 0.0f;
    }
    __syncthreads();
    float accl[TROWS] = {0.f, 0.f, 0.f, 0.f, 0.f, 0.f, 0.f, 0.f};
    float accr[TROWS] = {0.f, 0.f, 0.f, 0.f, 0.f, 0.f, 0.f, 0.f};
    for (int k = 0; k < IN_C; ++k) {
        float wl = Wl[k * IN_C + t];
        float wr = Wr[k * IN_C + t];
#pragma unroll
        for (int r = 0; r < TROWS; ++r) {
            float xv = xs[r][k];        // broadcast, conflict-free
            accl[r] = fmaf(xv, wl, accl[r]);
            accr[r] = fmaf(xv, wr, accr[r]);
        }
    }
#pragma unroll
    for (int r = 0; r < TROWS; ++r) {
        int row = row0 + r;
        if (row < n) {
            outl[(size_t)row * IN_C + t] = accl[r];
            outr[(size_t)row * IN_C + t] = accr[r];
        }
    }
}

// ---------- CSR build ----------
__global__ void hist_kernel(const int* __restrict__ dst, int* __restrict__ cnt, int E) {
    int e = blockIdx.x * blockDim.x + threadIdx.x;
    if (e < E) atomicAdd(&cnt[dst[e]], 1);
}

__global__ void scan_block_sums(const int* __restrict__ cnt, int* __restrict__ part, int n) {
    __shared__ int sdata[256];
    int t = threadIdx.x;
    int i = blockIdx.x * 256 + t;
    sdata[t] = (i < n) ? cnt[i] : 0;
    __syncthreads();
    for (int o = 128; o >= 1; o >>= 1) {
        if (t < o) sdata[t] += sdata[t + o];
        __syncthreads();
    }
    if (t == 0) part[blockIdx.x] = sdata[0];
}

__global__ void scan_part_excl(int* __restrict__ part, int nb) {  // single block, 1024 thr
    __shared__ int buf[1024];
    int t = threadIdx.x;
    int v = (t < nb) ? part[t] : 0;
    buf[t] = v;
    __syncthreads();
    for (int o = 1; o < 1024; o <<= 1) {
        int a = (t >= o) ? buf[t - o] : 0;
        __syncthreads();
        buf[t] += a;
        __syncthreads();
    }
    if (t < nb) part[t] = buf[t] - v;   // exclusive
}

__global__ void scan_final(const int* __restrict__ cnt, const int* __restrict__ part,
                           int* __restrict__ rowptr, int n) {
    __shared__ int buf[256];
    int t = threadIdx.x;
    int i = blockIdx.x * 256 + t;
    int v = (i < n) ? cnt[i] : 0;
    buf[t] = v;
    __syncthreads();
    for (int o = 1; o < 256; o <<= 1) {
        int a = (t >= o) ? buf[t - o] : 0;
        __syncthreads();
        buf[t] += a;
        __syncthreads();
    }
    int excl = part[blockIdx.x] + buf[t] - v;
    if (i < n) rowptr[i] = excl;
    if (i == n - 1) rowptr[n] = excl + v;
}

__global__ void scatter_csr(const int* __restrict__ dst,
                            const int* __restrict__ rowptr,
                            int* __restrict__ cursor,
                            int* __restrict__ eids, int E) {
    int e = blockIdx.x * blockDim.x + threadIdx.x;
    if (e >= E) return;
    int d = dst[e];
    int pos = atomicAdd(&cursor[d], 1);
    eids[rowptr[d] + pos] = e;
}

// ---------- fused score+softmax+aggregate, layer 1 (4 heads x 32ch) ----------
// block=128 (2 waves). Phase A: wave w computes edges w, w+2,... (2 edges in flight):
// lane l handles channels l (head l>>5) and 64+l (head 2+(l>>5)).
// Online softmax per head; LDS caches rows for the aggregation pass.
__global__ void node_fused1(const float* __restrict__ xl,
                            const float* __restrict__ xr,
                            const float* __restrict__ att,
                            const int* __restrict__ rowptr,
                            const int* __restrict__ eids,
                            const int* __restrict__ src,
                            const float* __restrict__ b,
                            float* __restrict__ hout, int N) {
    const int d = blockIdx.x;
    const int t = threadIdx.x;          // 0..127 -> output channel
    const int wv = t >> 6, l = t & 63;
    const int ht = t >> 5;              // head of this thread's channel
    const int beg = rowptr[d], end = rowptr[d + 1];
    __shared__ float rows[CAP][128];
    __shared__ float sc[CAP][HEADS];
    const float xr_lo = xr[(size_t)d * IN_C + l];
    const float xr_hi = xr[(size_t)d * IN_C + 64 + l];
    const float at_lo = att[l];
    const float at_hi = att[64 + l];
    float m = -1e30f, lsum = 0.f, acc = 0.f;
    for (int c0 = beg; c0 < end; c0 += CAP) {
        int nc = min(CAP, end - c0);
        for (int j = wv; j < nc; j += 2) {
            int e = eids[c0 + j];
            int s = src[e];
            float v0 = xl[(size_t)s * IN_C + l];
            float v1 = xl[(size_t)s * IN_C + 64 + l];
            rows[j][l] = v0;
            rows[j][64 + l] = v1;
            float f0 = v0 + xr_lo; f0 = (f0 > 0.f ? f0 : NEG_SLOPE * f0) * at_lo;
            float f1 = v1 + xr_hi; f1 = (f1 > 0.f ? f1 : NEG_SLOPE * f1) * at_hi;
#pragma unroll
            for (int o = 16; o >= 1; o >>= 1) {   // reduce within 32-lane head groups
                f0 += __shfl_xor(f0, o, 64);
                f1 += __shfl_xor(f1, o, 64);
            }
            if ((l & 31) == 0) {
                int g = l >> 5;                   // 0 or 1
                sc[j][g] = f0;                    // heads 0/1
                sc[j][2 + g] = f1;                // heads 2/3
            }
        }
        __syncthreads();
        float Mc = -1e30f;
        for (int j = 0; j < nc; ++j) Mc = fmaxf(Mc, sc[j][ht]);
        float newm = fmaxf(m, Mc);
        float factor = __expf(m - newm);
        acc *= factor; lsum *= factor;
        for (int j = 0; j < nc; ++j) {
            float w = __expf(sc[j][ht] - newm);
            lsum += w;
            acc = fmaf(w, rows[j][t], acc);
        }
        m = newm;
        __syncthreads();
    }
    float outv = (lsum > 0.f ? acc / lsum : 0.f) + b[t];
    hout[(size_t)d * IN_C + t] = (outv > 0.f) ? outv : expm1f(outv);  // bias+ELU fused
}

// ---------- fused score+softmax+aggregate, layer 2 (1 head x 128ch) ----------
__global__ void node_fused2(const float* __restrict__ xl,
                            const float* __restrict__ xr,
                            const float* __restrict__ att,
                            const int* __restrict__ rowptr,
                            const int* __restrict__ eids,
                            const int* __restrict__ src,
                            const float* __restrict__ b,
                            float* __restrict__ out, int N) {
    const int d = blockIdx.x;
    const int t = threadIdx.x;
    const int wv = t >> 6, l = t & 63;
    const int beg = rowptr[d], end = rowptr[d + 1];
    __shared__ float rows[CAP][128];
    __shared__ float sc[CAP];
    const float xr_lo = xr[(size_t)d * OUT_C + l];
    const float xr_hi = xr[(size_t)d * OUT_C + 64 + l];
    const float at_lo = att[l];
    const float at_hi = att[64 + l];
    float m = -1e30f, lsum = 0.f, acc = 0.f;
    for (int c0 = beg; c0 < end; c0 += CAP) {
        int nc = min(CAP, end - c0);
        for (int j = wv; j < nc; j += 2) {
            int e = eids[c0 + j];
            int s = src[e];
            float v0 = xl[(size_t)s * OUT_C + l];
            float v1 = xl[(size_t)s * OUT_C + 64 + l];
            rows[j][l] = v0;
            rows[j][64 + l] = v1;
            float f0 = v0 + xr_lo; f0 = (f0 > 0.f ? f0 : NEG_SLOPE * f0) * at_lo;
            float f1 = v1 + xr_hi; f1 = (f1 > 0.f ? f1 : NEG_SLOPE * f1) * at_hi;
            float f = f0 + f1;
#pragma unroll
            for (int o = 32; o >= 1; o >>= 1) f += __shfl_xor(f, o, 64);
            if (l == 0) sc[j] = f;
        }
        __syncthreads();
        float Mc = -1e30f;
        for (int j = 0; j < nc; ++j) Mc = fmaxf(Mc, sc[j]);
        float newm = fmaxf(m, Mc);
        float factor = __expf(m - newm);
        acc *= factor; lsum *= factor;
        for (int j = 0; j < nc; ++j) {
            float w = __expf(sc[j] - newm);
            lsum += w;
            acc = fmaf(w, rows[j][t], acc);
        }
        m = newm;
        __syncthreads();
    }
    out[(size_t)d * OUT_C + t] = (lsum > 0.f ? acc / lsum : 0.f) + b[t];
}

extern "C" void kernel_launch(void* const* d_in, const int* in_sizes, int n_in,
                              void* d_out, int out_size, void* d_ws, size_t ws_size,
                              hipStream_t stream) {
    const float* x    = (const float*)d_in[0];
    const int*   ei   = (const int*)d_in[1];
    const float* W1l  = (const float*)d_in[2];
    const float* W1r  = (const float*)d_in[3];
    const float* att1 = (const float*)d_in[4];
    const float* b1   = (const float*)d_in[5];
    const float* W2l  = (const float*)d_in[6];
    const float* W2r  = (const float*)d_in[7];
    const float* att2 = (const float*)d_in[8];
    const float* b2   = (const float*)d_in[9];

    const int N = in_sizes[0] / IN_C;
    const int E = in_sizes[1] / 2;
    const int* src = ei;
    const int* dst = ei + E;

    // workspace layout
    float* ws = (float*)d_ws;
    size_t o = 0;
    float* xl   = ws + o; o += (size_t)N * IN_C;   // x@Wl (layer1) / h@W2l (layer2)
    float* xr   = ws + o; o += (size_t)N * IN_C;   // x@Wr (layer1) / h@W2r (layer2)
    float* hbuf = ws + o; o += (size_t)N * IN_C;   // layer1 output h (post ELU)
    int* iws    = (int*)(ws + o);
    int* rowptr = iws;                    // N+1
    int* cnt    = iws + (N + 1);          // N   (cnt+cursor adjacent: one memset)
    int* cursor = iws + (N + 1) + N;      // N
    int* part   = iws + (N + 1) + 2 * N;  // <=1024 block partials
    int* eids   = iws + (N + 1) + 2 * N + 1024;  // E

    hipMemsetAsync(cnt, 0, (size_t)2 * N * 4, stream);   // cnt + cursor

    const int B = 256;
    const int nb = (N + 255) / 256;   // scan blocks (196 <= 1024)
    // ---- CSR by dst (shared by both layers) ----
    hist_kernel<<<(E + B - 1) / B, B, 0, stream>>>(dst, cnt, E);
    scan_block_sums<<<nb, 256, 0, stream>>>(cnt, part, N);
    scan_part_excl<<<1, 1024, 0, stream>>>(part, nb);
    scan_final<<<nb, 256, 0, stream>>>(cnt, part, rowptr, N);
    scatter_csr<<<(E + B - 1) / B, B, 0, stream>>>(dst, rowptr, cursor, eids, E);

    // ---- layer 1 ----
    transform_dual<<<(N + TROWS - 1) / TROWS, 128, 0, stream>>>(x, W1l, W1r, xl, xr, N);
    node_fused1<<<N, 128, 0, stream>>>(xl, xr, att1, rowptr, eids, src, b1, hbuf, N);

    // ---- layer 2 ----
    transform_dual<<<(N + TROWS - 1) / TROWS, 128, 0, stream>>>(hbuf, W2l, W2r, xl, xr, N);
    node_fused2<<<N, 128, 0, stream>>>(xl, xr, att2, rowptr, eids, src, b2, (float*)d_out, N);
}

// Round 4
// 560.555 us; speedup vs baseline: 20.5300x; 1.3917x over previous
//
#include <hip/hip_runtime.h>
#include <math.h>

#define IN_C 128
#define HID 32
#define HEADS 4
#define OUT_C 128
#define NEG_SLOPE 0.2f

// ---------- dual transform: out_l = x@Wl, out_r = x@Wr  (K=M=128) ----------
// 256 threads: col = t&127, row-half rh = t>>7. 16 rows/block halves W traffic.
#define TROWS 16
__global__ __launch_bounds__(256) void transform_dual(
        const float* __restrict__ x,
        const float* __restrict__ Wl,
        const float* __restrict__ Wr,
        float* __restrict__ outl,
        float* __restrict__ outr, int n) {
    __shared__ float xs[TROWS][IN_C];
    const int col = threadIdx.x & 127;
    const int rh  = threadIdx.x >> 7;        // 0 or 1
    const int row0 = blockIdx.x * TROWS;
#pragma unroll
    for (int r = 0; r < 8; ++r) {
        int row = row0 + rh * 8 + r;
        xs[rh * 8 + r][col] = (row < n) ? x[(size_t)row * IN_C + col] : 0.0f;
    }
    __syncthreads();
    float accl[8] = {0.f, 0.f, 0.f, 0.f, 0.f, 0.f, 0.f, 0.f};
    float accr[8] = {0.f, 0.f, 0.f, 0.f, 0.f, 0.f, 0.f, 0.f};
    for (int k = 0; k < IN_C; ++k) {
        float wl = Wl[k * IN_C + col];
        float wr = Wr[k * IN_C + col];
#pragma unroll
        for (int r = 0; r < 8; ++r) {
            float xv = xs[rh * 8 + r][k];    // wave-uniform broadcast
            accl[r] = fmaf(xv, wl, accl[r]);
            accr[r] = fmaf(xv, wr, accr[r]);
        }
    }
#pragma unroll
    for (int r = 0; r < 8; ++r) {
        int row = row0 + rh * 8 + r;
        if (row < n) {
            outl[(size_t)row * IN_C + col] = accl[r];
            outr[(size_t)row * IN_C + col] = accr[r];
        }
    }
}

// ---------- CSR build ----------
__global__ void hist_kernel(const int* __restrict__ dst, int* __restrict__ cnt, int E) {
    int e = blockIdx.x * blockDim.x + threadIdx.x;
    if (e < E) atomicAdd(&cnt[dst[e]], 1);
}

__global__ void scan_block_sums(const int* __restrict__ cnt, int* __restrict__ part, int n) {
    __shared__ int sdata[256];
    int t = threadIdx.x;
    int i = blockIdx.x * 256 + t;
    sdata[t] = (i < n) ? cnt[i] : 0;
    __syncthreads();
    for (int o = 128; o >= 1; o >>= 1) {
        if (t < o) sdata[t] += sdata[t + o];
        __syncthreads();
    }
    if (t == 0) part[blockIdx.x] = sdata[0];
}

__global__ void scan_part_excl(int* __restrict__ part, int nb) {  // single block, 1024 thr
    __shared__ int buf[1024];
    int t = threadIdx.x;
    int v = (t < nb) ? part[t] : 0;
    buf[t] = v;
    __syncthreads();
    for (int o = 1; o < 1024; o <<= 1) {
        int a = (t >= o) ? buf[t - o] : 0;
        __syncthreads();
        buf[t] += a;
        __syncthreads();
    }
    if (t < nb) part[t] = buf[t] - v;   // exclusive
}

__global__ void scan_final(const int* __restrict__ cnt, const int* __restrict__ part,
                           int* __restrict__ rowptr, int n) {
    __shared__ int buf[256];
    int t = threadIdx.x;
    int i = blockIdx.x * 256 + t;
    int v = (i < n) ? cnt[i] : 0;
    buf[t] = v;
    __syncthreads();
    for (int o = 1; o < 256; o <<= 1) {
        int a = (t >= o) ? buf[t - o] : 0;
        __syncthreads();
        buf[t] += a;
        __syncthreads();
    }
    int excl = part[blockIdx.x] + buf[t] - v;
    if (i < n) rowptr[i] = excl;
    if (i == n - 1) rowptr[n] = excl + v;
}

__global__ void scatter_csr(const int* __restrict__ dst,
                            const int* __restrict__ rowptr,
                            int* __restrict__ cursor,
                            int* __restrict__ eids, int E) {
    int e = blockIdx.x * blockDim.x + threadIdx.x;
    if (e >= E) return;
    int d = dst[e];
    int pos = atomicAdd(&cursor[d], 1);
    eids[rowptr[d] + pos] = e;
}

// ---------- fused score+softmax+aggregate, one WAVE per node ----------
// Lane l owns channels l and 64+l. 8 edges per unrolled batch, all in registers.
#define BATCH 8

// layer 1: 4 heads x 32ch. Channel l -> head l>>5; channel 64+l -> head 2+(l>>5).
__global__ __launch_bounds__(256) void node_fused1(
        const float* __restrict__ xl,
        const float* __restrict__ xr,
        const float* __restrict__ att,
        const int* __restrict__ rowptr,
        const int* __restrict__ eids,
        const int* __restrict__ src,
        const float* __restrict__ b,
        float* __restrict__ hout, int N) {
    const int wv = threadIdx.x >> 6;
    const int l  = threadIdx.x & 63;
    const int d  = blockIdx.x * 4 + wv;
    if (d >= N) return;
    const int beg = rowptr[d], end = rowptr[d + 1];
    const float xr_lo = xr[(size_t)d * IN_C + l];
    const float xr_hi = xr[(size_t)d * IN_C + 64 + l];
    const float at_lo = att[l];
    const float at_hi = att[64 + l];
    float m0 = -1e30f, ls0 = 0.f, a0 = 0.f;   // state for head of channel l
    float m1 = -1e30f, ls1 = 0.f, a1 = 0.f;   // state for head of channel 64+l
    for (int c0 = beg; c0 < end; c0 += BATCH) {
        float f0[BATCH], f1[BATCH], v0[BATCH], v1[BATCH];
#pragma unroll
        for (int i = 0; i < BATCH; ++i) {
            int j = c0 + i;
            bool ok = j < end;
            if (!ok) j = beg;
            int s = src[eids[j]];                       // wave-uniform -> scalar loads
            v0[i] = xl[(size_t)s * IN_C + l];
            v1[i] = xl[(size_t)s * IN_C + 64 + l];
            float g0 = v0[i] + xr_lo; g0 = (g0 > 0.f ? g0 : NEG_SLOPE * g0) * at_lo;
            float g1 = v1[i] + xr_hi; g1 = (g1 > 0.f ? g1 : NEG_SLOPE * g1) * at_hi;
#pragma unroll
            for (int o = 16; o >= 1; o >>= 1) {         // reduce within 32-lane head group
                g0 += __shfl_xor(g0, o, 64);
                g1 += __shfl_xor(g1, o, 64);
            }
            f0[i] = ok ? g0 : -1e30f;
            f1[i] = ok ? g1 : -1e30f;
        }
        float b0 = f0[0], b1 = f1[0];
#pragma unroll
        for (int i = 1; i < BATCH; ++i) { b0 = fmaxf(b0, f0[i]); b1 = fmaxf(b1, f1[i]); }
        float n0 = fmaxf(m0, b0), n1 = fmaxf(m1, b1);
        float fc0 = __expf(m0 - n0), fc1 = __expf(m1 - n1);
        ls0 *= fc0; a0 *= fc0;
        ls1 *= fc1; a1 *= fc1;
#pragma unroll
        for (int i = 0; i < BATCH; ++i) {
            float w0 = __expf(f0[i] - n0);
            float w1 = __expf(f1[i] - n1);
            ls0 += w0; a0 = fmaf(w0, v0[i], a0);
            ls1 += w1; a1 = fmaf(w1, v1[i], a1);
        }
        m0 = n0; m1 = n1;
    }
    float o0 = (ls0 > 0.f ? a0 / ls0 : 0.f) + b[l];
    float o1 = (ls1 > 0.f ? a1 / ls1 : 0.f) + b[64 + l];
    hout[(size_t)d * IN_C + l]      = (o0 > 0.f) ? o0 : expm1f(o0);   // bias+ELU
    hout[(size_t)d * IN_C + 64 + l] = (o1 > 0.f) ? o1 : expm1f(o1);
}

// layer 2: single head x 128ch (one score per edge, shared by both channels)
__global__ __launch_bounds__(256) void node_fused2(
        const float* __restrict__ xl,
        const float* __restrict__ xr,
        const float* __restrict__ att,
        const int* __restrict__ rowptr,
        const int* __restrict__ eids,
        const int* __restrict__ src,
        const float* __restrict__ b,
        float* __restrict__ out, int N) {
    const int wv = threadIdx.x >> 6;
    const int l  = threadIdx.x & 63;
    const int d  = blockIdx.x * 4 + wv;
    if (d >= N) return;
    const int beg = rowptr[d], end = rowptr[d + 1];
    const float xr_lo = xr[(size_t)d * OUT_C + l];
    const float xr_hi = xr[(size_t)d * OUT_C + 64 + l];
    const float at_lo = att[l];
    const float at_hi = att[64 + l];
    float m = -1e30f, ls = 0.f, a0 = 0.f, a1 = 0.f;
    for (int c0 = beg; c0 < end; c0 += BATCH) {
        float f[BATCH], v0[BATCH], v1[BATCH];
#pragma unroll
        for (int i = 0; i < BATCH; ++i) {
            int j = c0 + i;
            bool ok = j < end;
            if (!ok) j = beg;
            int s = src[eids[j]];
            v0[i] = xl[(size_t)s * OUT_C + l];
            v1[i] = xl[(size_t)s * OUT_C + 64 + l];
            float g0 = v0[i] + xr_lo; g0 = (g0 > 0.f ? g0 : NEG_SLOPE * g0) * at_lo;
            float g1 = v1[i] + xr_hi; g1 = (g1 > 0.f ? g1 : NEG_SLOPE * g1) * at_hi;
            float g = g0 + g1;
#pragma unroll
            for (int o = 32; o >= 1; o >>= 1) g += __shfl_xor(g, o, 64);
            f[i] = ok ? g : -1e30f;
        }
        float bm = f[0];
#pragma unroll
        for (int i = 1; i < BATCH; ++i) bm = fmaxf(bm, f[i]);
        float nm = fmaxf(m, bm);
        float fc = __expf(m - nm);
        ls *= fc; a0 *= fc; a1 *= fc;
#pragma unroll
        for (int i = 0; i < BATCH; ++i) {
            float w = __expf(f[i] - nm);
            ls += w;
            a0 = fmaf(w, v0[i], a0);
            a1 = fmaf(w, v1[i], a1);
        }
        m = nm;
    }
    float inv = (ls > 0.f) ? 1.f / ls : 0.f;
    out[(size_t)d * OUT_C + l]      = a0 * inv + b[l];
    out[(size_t)d * OUT_C + 64 + l] = a1 * inv + b[64 + l];
}

extern "C" void kernel_launch(void* const* d_in, const int* in_sizes, int n_in,
                              void* d_out, int out_size, void* d_ws, size_t ws_size,
                              hipStream_t stream) {
    const float* x    = (const float*)d_in[0];
    const int*   ei   = (const int*)d_in[1];
    const float* W1l  = (const float*)d_in[2];
    const float* W1r  = (const float*)d_in[3];
    const float* att1 = (const float*)d_in[4];
    const float* b1   = (const float*)d_in[5];
    const float* W2l  = (const float*)d_in[6];
    const float* W2r  = (const float*)d_in[7];
    const float* att2 = (const float*)d_in[8];
    const float* b2   = (const float*)d_in[9];

    const int N = in_sizes[0] / IN_C;
    const int E = in_sizes[1] / 2;
    const int* src = ei;
    const int* dst = ei + E;

    // workspace layout
    float* ws = (float*)d_ws;
    size_t o = 0;
    float* xl   = ws + o; o += (size_t)N * IN_C;   // x@Wl (layer1) / h@W2l (layer2)
    float* xr   = ws + o; o += (size_t)N * IN_C;   // x@Wr (layer1) / h@W2r (layer2)
    float* hbuf = ws + o; o += (size_t)N * IN_C;   // layer1 output h (post ELU)
    int* iws    = (int*)(ws + o);
    int* rowptr = iws;                    // N+1
    int* cnt    = iws + (N + 1);          // N   (cnt+cursor adjacent: one memset)
    int* cursor = iws + (N + 1) + N;      // N
    int* part   = iws + (N + 1) + 2 * N;  // <=1024 block partials
    int* eids   = iws + (N + 1) + 2 * N + 1024;  // E

    hipMemsetAsync(cnt, 0, (size_t)2 * N * 4, stream);   // cnt + cursor

    const int B = 256;
    const int nb = (N + 255) / 256;   // scan blocks (196 <= 1024)
    // ---- CSR by dst (shared by both layers) ----
    hist_kernel<<<(E + B - 1) / B, B, 0, stream>>>(dst, cnt, E);
    scan_block_sums<<<nb, 256, 0, stream>>>(cnt, part, N);
    scan_part_excl<<<1, 1024, 0, stream>>>(part, nb);
    scan_final<<<nb, 256, 0, stream>>>(cnt, part, rowptr, N);
    scatter_csr<<<(E + B - 1) / B, B, 0, stream>>>(dst, rowptr, cursor, eids, E);

    // ---- layer 1 ----
    transform_dual<<<(N + TROWS - 1) / TROWS, 256, 0, stream>>>(x, W1l, W1r, xl, xr, N);
    node_fused1<<<(N + 3) / 4, 256, 0, stream>>>(xl, xr, att1, rowptr, eids, src, b1, hbuf, N);

    // ---- layer 2 ----
    transform_dual<<<(N + TROWS - 1) / TROWS, 256, 0, stream>>>(hbuf, W2l, W2r, xl, xr, N);
    node_fused2<<<(N + 3) / 4, 256, 0, stream>>>(xl, xr, att2, rowptr, eids, src, b2, (float*)d_out, N);
}

// Round 5
// 425.025 us; speedup vs baseline: 27.0766x; 1.3189x over previous
//
#include <hip/hip_runtime.h>
#include <math.h>

#define IN_C 128
#define HID 32
#define HEADS 4
#define OUT_C 128
#define NEG_SLOPE 0.2f

// ---------- dual transform: out_l = x@Wl, out_r = x@Wr  (K=M=128) ----------
// 256 threads: col = t&127, row-half rh = t>>7. LDS x-tile read as float4 along k
// (ds_read_b128 broadcast) so the LDS pipe stops being the bottleneck.
#define TROWS 16
__global__ __launch_bounds__(256) void transform_dual(
        const float* __restrict__ x,
        const float* __restrict__ Wl,
        const float* __restrict__ Wr,
        float* __restrict__ outl,
        float* __restrict__ outr, int n) {
    __shared__ float xs[TROWS][IN_C];
    const int col = threadIdx.x & 127;
    const int rh  = threadIdx.x >> 7;        // 0 or 1
    const int row0 = blockIdx.x * TROWS;
#pragma unroll
    for (int r = 0; r < 8; ++r) {
        int row = row0 + rh * 8 + r;
        xs[rh * 8 + r][col] = (row < n) ? x[(size_t)row * IN_C + col] : 0.0f;
    }
    __syncthreads();
    float accl[8] = {0.f, 0.f, 0.f, 0.f, 0.f, 0.f, 0.f, 0.f};
    float accr[8] = {0.f, 0.f, 0.f, 0.f, 0.f, 0.f, 0.f, 0.f};
    for (int k0 = 0; k0 < IN_C; k0 += 4) {
        float wl[4], wr[4];
#pragma unroll
        for (int q = 0; q < 4; ++q) {
            wl[q] = Wl[(k0 + q) * IN_C + col];
            wr[q] = Wr[(k0 + q) * IN_C + col];
        }
#pragma unroll
        for (int r = 0; r < 8; ++r) {
            float4 xv = *(const float4*)&xs[rh * 8 + r][k0];   // b128 broadcast
            accl[r] = fmaf(xv.x, wl[0], accl[r]);
            accl[r] = fmaf(xv.y, wl[1], accl[r]);
            accl[r] = fmaf(xv.z, wl[2], accl[r]);
            accl[r] = fmaf(xv.w, wl[3], accl[r]);
            accr[r] = fmaf(xv.x, wr[0], accr[r]);
            accr[r] = fmaf(xv.y, wr[1], accr[r]);
            accr[r] = fmaf(xv.z, wr[2], accr[r]);
            accr[r] = fmaf(xv.w, wr[3], accr[r]);
        }
    }
#pragma unroll
    for (int r = 0; r < 8; ++r) {
        int row = row0 + rh * 8 + r;
        if (row < n) {
            outl[(size_t)row * IN_C + col] = accl[r];
            outr[(size_t)row * IN_C + col] = accr[r];
        }
    }
}

// ---------- CSR build ----------
__global__ void hist_kernel(const int* __restrict__ dst, int* __restrict__ cnt, int E) {
    int e = blockIdx.x * blockDim.x + threadIdx.x;
    if (e < E) atomicAdd(&cnt[dst[e]], 1);
}

__global__ void scan_block_sums(const int* __restrict__ cnt, int* __restrict__ part, int n) {
    __shared__ int sdata[256];
    int t = threadIdx.x;
    int i = blockIdx.x * 256 + t;
    sdata[t] = (i < n) ? cnt[i] : 0;
    __syncthreads();
    for (int o = 128; o >= 1; o >>= 1) {
        if (t < o) sdata[t] += sdata[t + o];
        __syncthreads();
    }
    if (t == 0) part[blockIdx.x] = sdata[0];
}

__global__ void scan_part_excl(int* __restrict__ part, int nb) {  // single block, 1024 thr
    __shared__ int buf[1024];
    int t = threadIdx.x;
    int v = (t < nb) ? part[t] : 0;
    buf[t] = v;
    __syncthreads();
    for (int o = 1; o < 1024; o <<= 1) {
        int a = (t >= o) ? buf[t - o] : 0;
        __syncthreads();
        buf[t] += a;
        __syncthreads();
    }
    if (t < nb) part[t] = buf[t] - v;   // exclusive
}

__global__ void scan_final(const int* __restrict__ cnt, const int* __restrict__ part,
                           int* __restrict__ rowptr, int n) {
    __shared__ int buf[256];
    int t = threadIdx.x;
    int i = blockIdx.x * 256 + t;
    int v = (i < n) ? cnt[i] : 0;
    buf[t] = v;
    __syncthreads();
    for (int o = 1; o < 256; o <<= 1) {
        int a = (t >= o) ? buf[t - o] : 0;
        __syncthreads();
        buf[t] += a;
        __syncthreads();
    }
    int excl = part[blockIdx.x] + buf[t] - v;
    if (i < n) rowptr[i] = excl;
    if (i == n - 1) rowptr[n] = excl + v;
}

// writes the GATHERED source index directly: gsrc[slot] = src[e]
__global__ void scatter_csr(const int* __restrict__ src,
                            const int* __restrict__ dst,
                            const int* __restrict__ rowptr,
                            int* __restrict__ cursor,
                            int* __restrict__ gsrc, int E) {
    int e = blockIdx.x * blockDim.x + threadIdx.x;
    if (e >= E) return;
    int d = dst[e];
    int pos = atomicAdd(&cursor[d], 1);
    gsrc[rowptr[d] + pos] = src[e];
}

// ---------- fused score+softmax+aggregate, one WAVE per node ----------
// Lane l owns channels 2l, 2l+1 (one dwordx2 per edge). 8 edges in flight.
#define BATCH 8

// layer 1: 4 heads x 32ch. Lane l's both channels belong to head l>>4 ->
// single softmax state per lane, head-reduce = 4 shuffles within 16 lanes.
__global__ __launch_bounds__(256) void node_fused1(
        const float* __restrict__ xl,
        const float* __restrict__ xr,
        const float* __restrict__ att,
        const int* __restrict__ rowptr,
        const int* __restrict__ gsrc,
        const float* __restrict__ b,
        float* __restrict__ hout, int N) {
    const int wv = threadIdx.x >> 6;
    const int l  = threadIdx.x & 63;
    const int d  = blockIdx.x * 4 + wv;
    if (d >= N) return;
    const int beg = rowptr[d], end = rowptr[d + 1];
    const float2 xr2 = *(const float2*)&xr[(size_t)d * IN_C + 2 * l];
    const float2 at2 = *(const float2*)&att[2 * l];
    float m = -1e30f, ls = 0.f, a0 = 0.f, a1 = 0.f;
    for (int c0 = beg; c0 < end; c0 += BATCH) {
        float f[BATCH], v0[BATCH], v1[BATCH];
#pragma unroll
        for (int i = 0; i < BATCH; ++i) {
            int j = c0 + i;
            bool ok = j < end;
            if (!ok) j = beg;
            int s = gsrc[j];                        // wave-uniform
            float2 v = *(const float2*)&xl[(size_t)s * IN_C + 2 * l];
            v0[i] = v.x; v1[i] = v.y;
            float g0 = v.x + xr2.x; g0 = (g0 > 0.f ? g0 : NEG_SLOPE * g0) * at2.x;
            float g1 = v.y + xr2.y; g1 = (g1 > 0.f ? g1 : NEG_SLOPE * g1) * at2.y;
            float g = g0 + g1;
#pragma unroll
            for (int o = 8; o >= 1; o >>= 1) g += __shfl_xor(g, o, 64);  // 16-lane head group
            f[i] = ok ? g : -1e30f;
        }
        float bm = f[0];
#pragma unroll
        for (int i = 1; i < BATCH; ++i) bm = fmaxf(bm, f[i]);
        float nm = fmaxf(m, bm);
        float fc = __expf(m - nm);
        ls *= fc; a0 *= fc; a1 *= fc;
#pragma unroll
        for (int i = 0; i < BATCH; ++i) {
            float w = __expf(f[i] - nm);
            ls += w;
            a0 = fmaf(w, v0[i], a0);
            a1 = fmaf(w, v1[i], a1);
        }
        m = nm;
    }
    float inv = (ls > 0.f) ? 1.f / ls : 0.f;
    const float2 b2v = *(const float2*)&b[2 * l];
    float o0 = a0 * inv + b2v.x;
    float o1 = a1 * inv + b2v.y;
    float2 outv;
    outv.x = (o0 > 0.f) ? o0 : expm1f(o0);   // fused bias + ELU
    outv.y = (o1 > 0.f) ? o1 : expm1f(o1);
    *(float2*)&hout[(size_t)d * IN_C + 2 * l] = outv;
}

// layer 2: single head x 128ch
__global__ __launch_bounds__(256) void node_fused2(
        const float* __restrict__ xl,
        const float* __restrict__ xr,
        const float* __restrict__ att,
        const int* __restrict__ rowptr,
        const int* __restrict__ gsrc,
        const float* __restrict__ b,
        float* __restrict__ out, int N) {
    const int wv = threadIdx.x >> 6;
    const int l  = threadIdx.x & 63;
    const int d  = blockIdx.x * 4 + wv;
    if (d >= N) return;
    const int beg = rowptr[d], end = rowptr[d + 1];
    const float2 xr2 = *(const float2*)&xr[(size_t)d * OUT_C + 2 * l];
    const float2 at2 = *(const float2*)&att[2 * l];
    float m = -1e30f, ls = 0.f, a0 = 0.f, a1 = 0.f;
    for (int c0 = beg; c0 < end; c0 += BATCH) {
        float f[BATCH], v0[BATCH], v1[BATCH];
#pragma unroll
        for (int i = 0; i < BATCH; ++i) {
            int j = c0 + i;
            bool ok = j < end;
            if (!ok) j = beg;
            int s = gsrc[j];
            float2 v = *(const float2*)&xl[(size_t)s * OUT_C + 2 * l];
            v0[i] = v.x; v1[i] = v.y;
            float g0 = v.x + xr2.x; g0 = (g0 > 0.f ? g0 : NEG_SLOPE * g0) * at2.x;
            float g1 = v.y + xr2.y; g1 = (g1 > 0.f ? g1 : NEG_SLOPE * g1) * at2.y;
            float g = g0 + g1;
#pragma unroll
            for (int o = 32; o >= 1; o >>= 1) g += __shfl_xor(g, o, 64);
            f[i] = ok ? g : -1e30f;
        }
        float bm = f[0];
#pragma unroll
        for (int i = 1; i < BATCH; ++i) bm = fmaxf(bm, f[i]);
        float nm = fmaxf(m, bm);
        float fc = __expf(m - nm);
        ls *= fc; a0 *= fc; a1 *= fc;
#pragma unroll
        for (int i = 0; i < BATCH; ++i) {
            float w = __expf(f[i] - nm);
            ls += w;
            a0 = fmaf(w, v0[i], a0);
            a1 = fmaf(w, v1[i], a1);
        }
        m = nm;
    }
    float inv = (ls > 0.f) ? 1.f / ls : 0.f;
    const float2 b2v = *(const float2*)&b[2 * l];
    float2 outv;
    outv.x = a0 * inv + b2v.x;
    outv.y = a1 * inv + b2v.y;
    *(float2*)&out[(size_t)d * OUT_C + 2 * l] = outv;
}

extern "C" void kernel_launch(void* const* d_in, const int* in_sizes, int n_in,
                              void* d_out, int out_size, void* d_ws, size_t ws_size,
                              hipStream_t stream) {
    const float* x    = (const float*)d_in[0];
    const int*   ei   = (const int*)d_in[1];
    const float* W1l  = (const float*)d_in[2];
    const float* W1r  = (const float*)d_in[3];
    const float* att1 = (const float*)d_in[4];
    const float* b1   = (const float*)d_in[5];
    const float* W2l  = (const float*)d_in[6];
    const float* W2r  = (const float*)d_in[7];
    const float* att2 = (const float*)d_in[8];
    const float* b2   = (const float*)d_in[9];

    const int N = in_sizes[0] / IN_C;
    const int E = in_sizes[1] / 2;
    const int* src = ei;
    const int* dst = ei + E;

    // workspace layout
    float* ws = (float*)d_ws;
    size_t o = 0;
    float* xl   = ws + o; o += (size_t)N * IN_C;   // x@Wl (layer1) / h@W2l (layer2)
    float* xr   = ws + o; o += (size_t)N * IN_C;   // x@Wr (layer1) / h@W2r (layer2)
    float* hbuf = ws + o; o += (size_t)N * IN_C;   // layer1 output h (post ELU)
    int* iws    = (int*)(ws + o);
    int* rowptr = iws;                    // N+1
    int* cnt    = iws + (N + 1);          // N   (cnt+cursor adjacent: one memset)
    int* cursor = iws + (N + 1) + N;      // N
    int* part   = iws + (N + 1) + 2 * N;  // <=1024 block partials
    int* gsrc   = iws + (N + 1) + 2 * N + 1024;  // E  (CSR-ordered source ids)

    hipMemsetAsync(cnt, 0, (size_t)2 * N * 4, stream);   // cnt + cursor

    const int B = 256;
    const int nb = (N + 255) / 256;   // scan blocks (196 <= 1024)
    // ---- CSR by dst (shared by both layers) ----
    hist_kernel<<<(E + B - 1) / B, B, 0, stream>>>(dst, cnt, E);
    scan_block_sums<<<nb, 256, 0, stream>>>(cnt, part, N);
    scan_part_excl<<<1, 1024, 0, stream>>>(part, nb);
    scan_final<<<nb, 256, 0, stream>>>(cnt, part, rowptr, N);
    scatter_csr<<<(E + B - 1) / B, B, 0, stream>>>(src, dst, rowptr, cursor, gsrc, E);

    // ---- layer 1 ----
    transform_dual<<<(N + TROWS - 1) / TROWS, 256, 0, stream>>>(x, W1l, W1r, xl, xr, N);
    node_fused1<<<(N + 3) / 4, 256, 0, stream>>>(xl, xr, att1, rowptr, gsrc, b1, hbuf, N);

    // ---- layer 2 ----
    transform_dual<<<(N + TROWS - 1) / TROWS, 256, 0, stream>>>(hbuf, W2l, W2r, xl, xr, N);
    node_fused2<<<(N + 3) / 4, 256, 0, stream>>>(xl, xr, att2, rowptr, gsrc, b2, (float*)d_out, N);
}